// Round 15
// baseline (345.850 us; speedup 1.0000x reference)
//
#include <hip/hip_runtime.h>

typedef short   bf16x8 __attribute__((ext_vector_type(8)));
typedef unsigned short u16x8 __attribute__((ext_vector_type(8)));
typedef float   f32x16 __attribute__((ext_vector_type(16)));

constexpr int NSUB  = 8;
constexpr int NCODE = 256;
constexpr int SDIM  = 96;
constexpr int EMB   = NSUB * SDIM;          // 768
constexpr float C_SHIFT = 192.0f;   // harmless shift baked into c2 (cancels in gaps)
constexpr float THR = 0.02f;        // validated recheck trigger (rounds 2-3-7..10,14)

constexpr int    CB_UNITS      = 8 * 6 * 2 * 64;                 // 6144 x 16B per subspace
constexpr size_t WS_FRAG_BYTES = (size_t)NSUB * CB_UNITS * 16;   // 786432
constexpr size_t WS_NEEDED     = WS_FRAG_BYTES + (size_t)NSUB * NCODE * 4;

__device__ __forceinline__ unsigned short f2bf(float v) {
    unsigned u = __builtin_bit_cast(unsigned, v);
    u = u + 0x7FFFu + ((u >> 16) & 1u);          // RNE
    return (unsigned short)(u >> 16);
}
__device__ __forceinline__ float bf2f(unsigned short h) {
    unsigned u = ((unsigned)h) << 16;
    return __builtin_bit_cast(float, u);
}

// ---------------- pre-kernel: pack codebook into ws (validated) ----------------
// frag unit u = ((t*6+s)*2+h)*64 + l : code=t*32+(l&31), k0=s*16+(l>>5)*8,
// value = h==0 ? hi : lo of (-cb). wsc2 = 0.5*||c||^2 + C_SHIFT (fp64).
__global__ __launch_bounds__(256) void pq_prep(const float* __restrict__ cb,
                                               unsigned short* __restrict__ wsf,
                                               float* __restrict__ wsc2)
{
    const int m   = (int)blockIdx.x;
    const int tid = (int)threadIdx.x;
    {
        const float* c = cb + ((size_t)m * NCODE + tid) * SDIM;
        double s = 0.0;
        for (int k = 0; k < SDIM; ++k) { double v = (double)c[k]; s += v * v; }
        wsc2[m * NCODE + tid] = (float)(0.5 * s + (double)C_SHIFT);
    }
    for (int i = 0; i < 24; ++i) {
        int u  = i * 256 + tid;
        int l  = u & 63;
        int c6 = u >> 6;
        int h  = c6 & 1; c6 >>= 1;
        int s  = c6 % 6;
        int t  = c6 / 6;
        int code = t * 32 + (l & 31);
        int k0   = s * 16 + (l >> 5) * 8;
        const float* src = cb + (size_t)m * NCODE * SDIM + (size_t)code * SDIM + k0;
        u16x8 o;
        #pragma unroll
        for (int j = 0; j < 8; ++j) {
            float v = -src[j];
            unsigned short hb = f2bf(v);
            o[j] = (h == 0) ? hb : f2bf(v - bf2f(hb));
        }
        *(u16x8*)(wsf + ((size_t)m * CB_UNITS + u) * 8) = o;
    }
}

// ------ main: one wave owns (m, 32 rows). NO LDS, NO barriers.           ------
// ------ Byte-identical numerics to R10/R14; cb frags loaded 2-at-a-time  ------
// ------ to cut peak liveness; VGPR capped at 73 => 7 waves/SIMD.         ------
__global__ __launch_bounds__(128, 7) void pq_mfma13(
    const float* __restrict__ emb,
    const float* __restrict__ cb,
    const unsigned short* __restrict__ wsf,
    const float* __restrict__ wsc2,
    float* __restrict__ out,
    int nrows,
    int rowblks)
{
    const int tid  = (int)threadIdx.x;
    const int lane = tid & 63;
    const int hib  = lane >> 5;
    const int widx = (int)blockIdx.x * 2 + (tid >> 6);
    if (widx >= NSUB * rowblks) return;
    const int m    = widx / rowblks;            // waves of one m are contiguous
    const int rb   = widx % rowblks;
    const int row0 = rb * 32;

    const unsigned short* wb = wsf + (size_t)m * CB_UNITS * 8;
    const float* c2p = wsc2 + m * NCODE;

    // ---- load this lane's x fragments straight from emb; hi/lo split in regs ----
    // lane l holds row (l&31), dims s*16 + (l>>5)*8 + [0..8)  (validated B layout)
    bf16x8 xh[6], xl[6];
    {
        int r = row0 + (lane & 31);
        if (r >= nrows) r = nrows - 1;
        const float* xr = emb + (size_t)r * EMB + m * SDIM + hib * 8;
        #pragma unroll
        for (int s = 0; s < 6; ++s) {
            float4 v0 = *(const float4*)(xr + s * 16);
            float4 v1 = *(const float4*)(xr + s * 16 + 4);
            float v[8] = { v0.x, v0.y, v0.z, v0.w, v1.x, v1.y, v1.z, v1.w };
            #pragma unroll
            for (int j = 0; j < 8; ++j) {
                unsigned short hb = f2bf(v[j]);
                xh[s][j] = (short)hb;
                xl[s][j] = (short)f2bf(v[j] - bf2f(hb));
            }
        }
    }

    // ---- 4 t-pairs: acc init from c2, 36 MFMA, serial scan (code-ascending) ----
    float b1 = 3.4e38f, b2 = 3.4e38f;
    int   i1 = 1 << 30, i2 = 1 << 30;
    #pragma unroll 1
    for (int p = 0; p < 4; ++p) {
        const int t0 = p * 2, t1 = t0 + 1;
        f32x16 a0, a1;
        #pragma unroll
        for (int rq = 0; rq < 4; ++rq) {
            float4 q0 = *(const float4*)(c2p + t0 * 32 + rq * 8 + hib * 4);
            float4 q1 = *(const float4*)(c2p + t1 * 32 + rq * 8 + hib * 4);
            a0[rq*4+0]=q0.x; a0[rq*4+1]=q0.y; a0[rq*4+2]=q0.z; a0[rq*4+3]=q0.w;
            a1[rq*4+0]=q1.x; a1[rq*4+1]=q1.y; a1[rq*4+2]=q1.z; a1[rq*4+3]=q1.w;
        }
        __builtin_amdgcn_s_setprio(1);
        #pragma unroll
        for (int s = 0; s < 6; ++s) {
            // 2-at-a-time fragment loads: halves peak frag liveness (16 -> 8 regs)
            {
                bf16x8 ah0 = *(const bf16x8*)(wb + (size_t)((((t0 * 6 + s) * 2) + 0) * 64 + lane) * 8);
                bf16x8 al0 = *(const bf16x8*)(wb + (size_t)((((t0 * 6 + s) * 2) + 1) * 64 + lane) * 8);
                a0 = __builtin_amdgcn_mfma_f32_32x32x16_bf16(ah0, xh[s], a0, 0, 0, 0);
                a0 = __builtin_amdgcn_mfma_f32_32x32x16_bf16(al0, xh[s], a0, 0, 0, 0);
                a0 = __builtin_amdgcn_mfma_f32_32x32x16_bf16(ah0, xl[s], a0, 0, 0, 0);
            }
            {
                bf16x8 ah1 = *(const bf16x8*)(wb + (size_t)((((t1 * 6 + s) * 2) + 0) * 64 + lane) * 8);
                bf16x8 al1 = *(const bf16x8*)(wb + (size_t)((((t1 * 6 + s) * 2) + 1) * 64 + lane) * 8);
                a1 = __builtin_amdgcn_mfma_f32_32x32x16_bf16(ah1, xh[s], a1, 0, 0, 0);
                a1 = __builtin_amdgcn_mfma_f32_32x32x16_bf16(al1, xh[s], a1, 0, 0, 0);
                a1 = __builtin_amdgcn_mfma_f32_32x32x16_bf16(ah1, xl[s], a1, 0, 0, 0);
            }
        }
        __builtin_amdgcn_s_setprio(0);
        // serial scan, ascending code order per lane (first-min tie rule)
        #pragma unroll
        for (int r = 0; r < 16; ++r) {
            float sv = a0[r];
            int   kv = t0 * 32 + (r & 3) + 8 * (r >> 2) + hib * 4;
            if (sv < b1)      { b2 = b1; i2 = i1; b1 = sv; i1 = kv; }
            else if (sv < b2) { b2 = sv; i2 = kv; }
        }
        #pragma unroll
        for (int r = 0; r < 16; ++r) {
            float sv = a1[r];
            int   kv = t1 * 32 + (r & 3) + 8 * (r >> 2) + hib * 4;
            if (sv < b1)      { b2 = b1; i2 = i1; b1 = sv; i1 = kv; }
            else if (sv < b2) { b2 = sv; i2 = kv; }
        }
    }
    {   // merge lane^32 partner (same rows, other hib codes) — validated code
        float ob1 = __shfl_xor(b1, 32);
        int   oi1 = __shfl_xor(i1, 32);
        float ob2 = __shfl_xor(b2, 32);
        int   oi2 = __shfl_xor(i2, 32);
        bool o1_better = (ob1 < b1) || (ob1 == b1 && oi1 < i1);
        if (o1_better) {
            bool mine_better = (b1 < ob2) || (b1 == ob2 && i1 < oi2);
            if (mine_better) { b2 = b1; i2 = i1; } else { b2 = ob2; i2 = oi2; }
            b1 = ob1; i1 = oi1;
        } else {
            if ((ob1 < b2) || (ob1 == b2 && oi1 < i2)) { b2 = ob1; i2 = oi1; }
        }
    }

    // ---- cheap top-2 fp64 recheck (validated; ~1-2% trigger; uniform 96-iter loop) ----
    {
        int grow = row0 + (lane & 31);
        if (lane < 32 && grow < nrows && (b2 - b1 < THR)) {
            const float* xr = emb + (size_t)grow * EMB + m * SDIM;
            const float* ca = cb + ((size_t)m * NCODE + i1) * SDIM;
            const float* cbv = cb + ((size_t)m * NCODE + i2) * SDIM;
            double da = 0.0, db = 0.0;
            for (int kk = 0; kk < SDIM; ++kk) {
                double ea = (double)xr[kk] - (double)ca[kk];
                double eb = (double)xr[kk] - (double)cbv[kk];
                da += ea * ea; db += eb * eb;
            }
            if (db < da || (db == da && i2 < i1)) i1 = i2;
        }
    }

    // ---- gather + coalesced write-out (24 lanes = 384B runs per row) ----
    #pragma unroll
    for (int ii = 0; ii < 12; ++ii) {
        int Q = ii * 64 + lane;                 // 768 = 32 rows x 24 float4
        int r = Q / 24, f = Q % 24;
        int grow = row0 + r;
        int k = __shfl(i1, r);                  // winner held by lane r (<32)
        if (grow < nrows) {
            float4 v = *(const float4*)(cb + ((size_t)m * NCODE + k) * SDIM + f * 4);
            *(float4*)(out + (size_t)grow * EMB + m * SDIM + f * 4) = v;
        }
    }
}

// ---------------- fallback (round-2 kernel, validated) ----------------
__global__ __launch_bounds__(256) void pq_argmin_kernel(
    const float* __restrict__ emb, const float* __restrict__ cb,
    float* __restrict__ out, int nrows)
{
    const int m   = (int)(blockIdx.x & 7);
    const int row = (int)(blockIdx.x >> 3) * 256 + (int)threadIdx.x;
    const float* __restrict__ cbm = cb + (size_t)m * (NCODE * SDIM);
    __shared__ float half_c2[NCODE];
    {
        const int k = (int)threadIdx.x;
        const float* c = cbm + k * SDIM;
        float s = 0.f;
        #pragma unroll
        for (int i = 0; i < SDIM; i += 4) {
            const float4 v = *reinterpret_cast<const float4*>(c + i);
            s = fmaf(v.x, v.x, s); s = fmaf(v.y, v.y, s);
            s = fmaf(v.z, v.z, s); s = fmaf(v.w, v.w, s);
        }
        half_c2[k] = 0.5f * s;
    }
    __syncthreads();
    if (row >= nrows) return;
    float x[SDIM];
    {
        const float* xr = emb + (size_t)row * EMB + m * SDIM;
        #pragma unroll
        for (int i = 0; i < SDIM; i += 4) {
            const float4 v = *reinterpret_cast<const float4*>(xr + i);
            x[i+0] = v.x; x[i+1] = v.y; x[i+2] = v.z; x[i+3] = v.w;
        }
    }
    float best = 3.4e38f, best2 = 3.4e38f;
    int bestk = 0, bestk2 = 0;
    #pragma unroll 1
    for (int k = 0; k < NCODE; k += 4) {
        const float* c0 = cbm + (k + 0) * SDIM;
        const float* c1 = cbm + (k + 1) * SDIM;
        const float* c2 = cbm + (k + 2) * SDIM;
        const float* c3 = cbm + (k + 3) * SDIM;
        float a0 = 0.f, a1 = 0.f, a2 = 0.f, a3 = 0.f;
        #pragma unroll
        for (int i = 0; i < SDIM; i += 4) {
            const float4 v0 = *reinterpret_cast<const float4*>(c0 + i);
            const float4 v1 = *reinterpret_cast<const float4*>(c1 + i);
            const float4 v2 = *reinterpret_cast<const float4*>(c2 + i);
            const float4 v3 = *reinterpret_cast<const float4*>(c3 + i);
            a0 = fmaf(x[i+0], v0.x, a0); a0 = fmaf(x[i+1], v0.y, a0);
            a0 = fmaf(x[i+2], v0.z, a0); a0 = fmaf(x[i+3], v0.w, a0);
            a1 = fmaf(x[i+0], v1.x, a1); a1 = fmaf(x[i+1], v1.y, a1);
            a1 = fmaf(x[i+2], v1.z, a1); a1 = fmaf(x[i+3], v1.w, a1);
            a2 = fmaf(x[i+0], v2.x, a2); a2 = fmaf(x[i+1], v2.y, a2);
            a2 = fmaf(x[i+2], v2.z, a2); a2 = fmaf(x[i+3], v2.w, a2);
            a3 = fmaf(x[i+0], v3.x, a3); a3 = fmaf(x[i+1], v3.y, a3);
            a3 = fmaf(x[i+2], v3.z, a3); a3 = fmaf(x[i+3], v3.w, a3);
        }
        const float s[4] = { half_c2[k+0] - a0, half_c2[k+1] - a1,
                             half_c2[k+2] - a2, half_c2[k+3] - a3 };
        #pragma unroll
        for (int j = 0; j < 4; ++j) {
            if (s[j] < best)       { best2 = best; bestk2 = bestk; best = s[j]; bestk = k + j; }
            else if (s[j] < best2) { best2 = s[j]; bestk2 = k + j; }
        }
    }
    if (best2 - best < 0.02f) {
        const float* ca = cbm + bestk  * SDIM;
        const float* cbv = cbm + bestk2 * SDIM;
        double da = 0.0, db = 0.0;
        for (int i = 0; i < SDIM; ++i) {
            const double ea = (double)x[i] - (double)ca[i];
            const double eb = (double)x[i] - (double)cbv[i];
            da += ea * ea; db += eb * eb;
        }
        if (db < da || (db == da && bestk2 < bestk)) bestk = bestk2;
    }
    const float* cbest = cbm + bestk * SDIM;
    float* o = out + (size_t)row * EMB + m * SDIM;
    #pragma unroll
    for (int i = 0; i < SDIM; i += 4)
        *reinterpret_cast<float4*>(o + i) = *reinterpret_cast<const float4*>(cbest + i);
}

extern "C" void kernel_launch(void* const* d_in, const int* in_sizes, int n_in,
                              void* d_out, int out_size, void* d_ws, size_t ws_size,
                              hipStream_t stream) {
    const float* emb = (const float*)d_in[0];
    const float* cb  = (const float*)d_in[1];
    float* out = (float*)d_out;
    const int nrows = in_sizes[0] / EMB;    // 65536

    if (ws_size < WS_NEEDED) {
        const int rowBlocks = (nrows + 255) / 256;
        pq_argmin_kernel<<<dim3(rowBlocks * NSUB), dim3(256), 0, stream>>>(emb, cb, out, nrows);
        return;
    }

    unsigned short* wsf = (unsigned short*)d_ws;
    float* wsc2 = (float*)((char*)d_ws + WS_FRAG_BYTES);

    pq_prep<<<dim3(NSUB), dim3(256), 0, stream>>>(cb, wsf, wsc2);

    const int rowblks = (nrows + 31) / 32;              // 2048
    const int nwaves  = rowblks * NSUB;                 // 16384
    const int nb      = (nwaves + 1) / 2;               // 8192 blocks of 128
    pq_mfma13<<<dim3(nb), dim3(128), 0, stream>>>(emb, cb, wsf, wsc2, out, nrows, rowblks);
}

// Round 16
// 216.804 us; speedup vs baseline: 1.5952x; 1.5952x over previous
//
#include <hip/hip_runtime.h>

typedef short   bf16x8 __attribute__((ext_vector_type(8)));
typedef unsigned short u16x8 __attribute__((ext_vector_type(8)));
typedef float   f32x16 __attribute__((ext_vector_type(16)));

constexpr int NSUB  = 8;
constexpr int NCODE = 256;
constexpr int SDIM  = 96;
constexpr int EMB   = NSUB * SDIM;          // 768
constexpr float C_SHIFT = 192.0f;   // harmless shift baked into c2 (cancels in gaps)
constexpr float THR = 0.02f;        // validated recheck trigger (rounds 2-3-7..10,14)

constexpr int NROWS_FIX   = 65536;          // harness shape (16 x 4096)
constexpr int ROWBLKS_FIX = NROWS_FIX / 32; // 2048

constexpr int    CB_UNITS      = 8 * 6 * 2 * 64;                 // 6144 x 16B per subspace
constexpr size_t WS_FRAG_BYTES = (size_t)NSUB * CB_UNITS * 16;   // 786432
constexpr size_t WS_NEEDED     = WS_FRAG_BYTES + (size_t)NSUB * NCODE * 4;

__device__ __forceinline__ unsigned short f2bf(float v) {
    unsigned u = __builtin_bit_cast(unsigned, v);
    u = u + 0x7FFFu + ((u >> 16) & 1u);          // RNE
    return (unsigned short)(u >> 16);
}
__device__ __forceinline__ float bf2f(unsigned short h) {
    unsigned u = ((unsigned)h) << 16;
    return __builtin_bit_cast(float, u);
}

// ---------------- pre-kernel: pack codebook into ws (validated) ----------------
// frag unit u = ((t*6+s)*2+h)*64 + l : code=t*32+(l&31), k0=s*16+(l>>5)*8,
// value = h==0 ? hi : lo of (-cb). wsc2 = 0.5*||c||^2 + C_SHIFT (fp64).
__global__ __launch_bounds__(256) void pq_prep(const float* __restrict__ cb,
                                               unsigned short* __restrict__ wsf,
                                               float* __restrict__ wsc2)
{
    const int m   = (int)blockIdx.x;
    const int tid = (int)threadIdx.x;
    {
        const float* c = cb + ((size_t)m * NCODE + tid) * SDIM;
        double s = 0.0;
        for (int k = 0; k < SDIM; ++k) { double v = (double)c[k]; s += v * v; }
        wsc2[m * NCODE + tid] = (float)(0.5 * s + (double)C_SHIFT);
    }
    for (int i = 0; i < 24; ++i) {
        int u  = i * 256 + tid;
        int l  = u & 63;
        int c6 = u >> 6;
        int h  = c6 & 1; c6 >>= 1;
        int s  = c6 % 6;
        int t  = c6 / 6;
        int code = t * 32 + (l & 31);
        int k0   = s * 16 + (l >> 5) * 8;
        const float* src = cb + (size_t)m * NCODE * SDIM + (size_t)code * SDIM + k0;
        u16x8 o;
        #pragma unroll
        for (int j = 0; j < 8; ++j) {
            float v = -src[j];
            unsigned short hb = f2bf(v);
            o[j] = (h == 0) ? hb : f2bf(v - bf2f(hb));
        }
        *(u16x8*)(wsf + ((size_t)m * CB_UNITS + u) * 8) = o;
    }
}

// ------ main: one wave owns (m, 32 rows). NO LDS, NO barriers.           ------
// ------ Byte-identical numerics to R10/R14; SHAPE-SPECIALIZED (nrows =   ------
// ------ 65536): no div/mod, no bounds checks -> lower VGPR demand.       ------
__global__ __launch_bounds__(128) void pq_mfma14(
    const float* __restrict__ emb,
    const float* __restrict__ cb,
    const unsigned short* __restrict__ wsf,
    const float* __restrict__ wsc2,
    float* __restrict__ out)
{
    const int tid  = (int)threadIdx.x;
    const int lane = tid & 63;
    const int hib  = lane >> 5;
    const int widx = (int)blockIdx.x * 2 + (tid >> 6);   // [0, 16384)
    const int m    = widx >> 11;                          // / ROWBLKS_FIX
    const int rb   = widx & (ROWBLKS_FIX - 1);
    const int row0 = rb * 32;

    const unsigned short* wb = wsf + (size_t)m * CB_UNITS * 8;
    const float* c2p = wsc2 + m * NCODE;

    // ---- load this lane's x fragments straight from emb; hi/lo split in regs ----
    // lane l holds row (l&31), dims s*16 + (l>>5)*8 + [0..8)  (validated B layout)
    bf16x8 xh[6], xl[6];
    {
        const float* xr = emb + (size_t)(row0 + (lane & 31)) * EMB + m * SDIM + hib * 8;
        #pragma unroll
        for (int s = 0; s < 6; ++s) {
            float4 v0 = *(const float4*)(xr + s * 16);
            float4 v1 = *(const float4*)(xr + s * 16 + 4);
            float v[8] = { v0.x, v0.y, v0.z, v0.w, v1.x, v1.y, v1.z, v1.w };
            #pragma unroll
            for (int j = 0; j < 8; ++j) {
                unsigned short hb = f2bf(v[j]);
                xh[s][j] = (short)hb;
                xl[s][j] = (short)f2bf(v[j] - bf2f(hb));
            }
        }
    }

    // ---- 4 t-pairs: acc init from c2, 36 MFMA, serial scan (code-ascending) ----
    float b1 = 3.4e38f, b2 = 3.4e38f;
    int   i1 = 1 << 30, i2 = 1 << 30;
    #pragma unroll 1
    for (int p = 0; p < 4; ++p) {
        const int t0 = p * 2, t1 = t0 + 1;
        f32x16 a0, a1;
        #pragma unroll
        for (int rq = 0; rq < 4; ++rq) {
            float4 q0 = *(const float4*)(c2p + t0 * 32 + rq * 8 + hib * 4);
            float4 q1 = *(const float4*)(c2p + t1 * 32 + rq * 8 + hib * 4);
            a0[rq*4+0]=q0.x; a0[rq*4+1]=q0.y; a0[rq*4+2]=q0.z; a0[rq*4+3]=q0.w;
            a1[rq*4+0]=q1.x; a1[rq*4+1]=q1.y; a1[rq*4+2]=q1.z; a1[rq*4+3]=q1.w;
        }
        #pragma unroll
        for (int s = 0; s < 6; ++s) {
            bf16x8 ah0 = *(const bf16x8*)(wb + (size_t)((((t0 * 6 + s) * 2) + 0) * 64 + lane) * 8);
            bf16x8 al0 = *(const bf16x8*)(wb + (size_t)((((t0 * 6 + s) * 2) + 1) * 64 + lane) * 8);
            bf16x8 ah1 = *(const bf16x8*)(wb + (size_t)((((t1 * 6 + s) * 2) + 0) * 64 + lane) * 8);
            bf16x8 al1 = *(const bf16x8*)(wb + (size_t)((((t1 * 6 + s) * 2) + 1) * 64 + lane) * 8);
            a0 = __builtin_amdgcn_mfma_f32_32x32x16_bf16(ah0, xh[s], a0, 0, 0, 0);
            a1 = __builtin_amdgcn_mfma_f32_32x32x16_bf16(ah1, xh[s], a1, 0, 0, 0);
            a0 = __builtin_amdgcn_mfma_f32_32x32x16_bf16(al0, xh[s], a0, 0, 0, 0);
            a1 = __builtin_amdgcn_mfma_f32_32x32x16_bf16(al1, xh[s], a1, 0, 0, 0);
            a0 = __builtin_amdgcn_mfma_f32_32x32x16_bf16(ah0, xl[s], a0, 0, 0, 0);
            a1 = __builtin_amdgcn_mfma_f32_32x32x16_bf16(ah1, xl[s], a1, 0, 0, 0);
        }
        // serial scan, ascending code order per lane (first-min tie rule)
        #pragma unroll
        for (int r = 0; r < 16; ++r) {
            float sv = a0[r];
            int   kv = t0 * 32 + (r & 3) + 8 * (r >> 2) + hib * 4;
            if (sv < b1)      { b2 = b1; i2 = i1; b1 = sv; i1 = kv; }
            else if (sv < b2) { b2 = sv; i2 = kv; }
        }
        #pragma unroll
        for (int r = 0; r < 16; ++r) {
            float sv = a1[r];
            int   kv = t1 * 32 + (r & 3) + 8 * (r >> 2) + hib * 4;
            if (sv < b1)      { b2 = b1; i2 = i1; b1 = sv; i1 = kv; }
            else if (sv < b2) { b2 = sv; i2 = kv; }
        }
    }
    {   // merge lane^32 partner (same rows, other hib codes) — validated code
        float ob1 = __shfl_xor(b1, 32);
        int   oi1 = __shfl_xor(i1, 32);
        float ob2 = __shfl_xor(b2, 32);
        int   oi2 = __shfl_xor(i2, 32);
        bool o1_better = (ob1 < b1) || (ob1 == b1 && oi1 < i1);
        if (o1_better) {
            bool mine_better = (b1 < ob2) || (b1 == ob2 && i1 < oi2);
            if (mine_better) { b2 = b1; i2 = i1; } else { b2 = ob2; i2 = oi2; }
            b1 = ob1; i1 = oi1;
        } else {
            if ((ob1 < b2) || (ob1 == b2 && oi1 < i2)) { b2 = ob1; i2 = oi1; }
        }
    }

    // ---- cheap top-2 fp64 recheck (validated; ~1-2% trigger; uniform 96-iter loop) ----
    {
        if (lane < 32 && (b2 - b1 < THR)) {
            const float* xr = emb + (size_t)(row0 + lane) * EMB + m * SDIM;
            const float* ca = cb + ((size_t)m * NCODE + i1) * SDIM;
            const float* cbv = cb + ((size_t)m * NCODE + i2) * SDIM;
            double da = 0.0, db = 0.0;
            for (int kk = 0; kk < SDIM; ++kk) {
                double ea = (double)xr[kk] - (double)ca[kk];
                double eb = (double)xr[kk] - (double)cbv[kk];
                da += ea * ea; db += eb * eb;
            }
            if (db < da || (db == da && i2 < i1)) i1 = i2;
        }
    }

    // ---- gather + coalesced write-out (24 lanes = 384B runs per row) ----
    #pragma unroll
    for (int ii = 0; ii < 12; ++ii) {
        int Q = ii * 64 + lane;                 // 768 = 32 rows x 24 float4
        int r = Q / 24, f = Q % 24;
        int k = __shfl(i1, r);                  // winner held by lane r (<32)
        float4 v = *(const float4*)(cb + ((size_t)m * NCODE + k) * SDIM + f * 4);
        *(float4*)(out + (size_t)(row0 + r) * EMB + m * SDIM + f * 4) = v;
    }
}

// ---------------- fallback (round-2 kernel, validated) ----------------
__global__ __launch_bounds__(256) void pq_argmin_kernel(
    const float* __restrict__ emb, const float* __restrict__ cb,
    float* __restrict__ out, int nrows)
{
    const int m   = (int)(blockIdx.x & 7);
    const int row = (int)(blockIdx.x >> 3) * 256 + (int)threadIdx.x;
    const float* __restrict__ cbm = cb + (size_t)m * (NCODE * SDIM);
    __shared__ float half_c2[NCODE];
    {
        const int k = (int)threadIdx.x;
        const float* c = cbm + k * SDIM;
        float s = 0.f;
        #pragma unroll
        for (int i = 0; i < SDIM; i += 4) {
            const float4 v = *reinterpret_cast<const float4*>(c + i);
            s = fmaf(v.x, v.x, s); s = fmaf(v.y, v.y, s);
            s = fmaf(v.z, v.z, s); s = fmaf(v.w, v.w, s);
        }
        half_c2[k] = 0.5f * s;
    }
    __syncthreads();
    if (row >= nrows) return;
    float x[SDIM];
    {
        const float* xr = emb + (size_t)row * EMB + m * SDIM;
        #pragma unroll
        for (int i = 0; i < SDIM; i += 4) {
            const float4 v = *reinterpret_cast<const float4*>(xr + i);
            x[i+0] = v.x; x[i+1] = v.y; x[i+2] = v.z; x[i+3] = v.w;
        }
    }
    float best = 3.4e38f, best2 = 3.4e38f;
    int bestk = 0, bestk2 = 0;
    #pragma unroll 1
    for (int k = 0; k < NCODE; k += 4) {
        const float* c0 = cbm + (k + 0) * SDIM;
        const float* c1 = cbm + (k + 1) * SDIM;
        const float* c2 = cbm + (k + 2) * SDIM;
        const float* c3 = cbm + (k + 3) * SDIM;
        float a0 = 0.f, a1 = 0.f, a2 = 0.f, a3 = 0.f;
        #pragma unroll
        for (int i = 0; i < SDIM; i += 4) {
            const float4 v0 = *reinterpret_cast<const float4*>(c0 + i);
            const float4 v1 = *reinterpret_cast<const float4*>(c1 + i);
            const float4 v2 = *reinterpret_cast<const float4*>(c2 + i);
            const float4 v3 = *reinterpret_cast<const float4*>(c3 + i);
            a0 = fmaf(x[i+0], v0.x, a0); a0 = fmaf(x[i+1], v0.y, a0);
            a0 = fmaf(x[i+2], v0.z, a0); a0 = fmaf(x[i+3], v0.w, a0);
            a1 = fmaf(x[i+0], v1.x, a1); a1 = fmaf(x[i+1], v1.y, a1);
            a1 = fmaf(x[i+2], v1.z, a1); a1 = fmaf(x[i+3], v1.w, a1);
            a2 = fmaf(x[i+0], v2.x, a2); a2 = fmaf(x[i+1], v2.y, a2);
            a2 = fmaf(x[i+2], v2.z, a2); a2 = fmaf(x[i+3], v2.w, a2);
            a3 = fmaf(x[i+0], v3.x, a3); a3 = fmaf(x[i+1], v3.y, a3);
            a3 = fmaf(x[i+2], v3.z, a3); a3 = fmaf(x[i+3], v3.w, a3);
        }
        const float s[4] = { half_c2[k+0] - a0, half_c2[k+1] - a1,
                             half_c2[k+2] - a2, half_c2[k+3] - a3 };
        #pragma unroll
        for (int j = 0; j < 4; ++j) {
            if (s[j] < best)       { best2 = best; bestk2 = bestk; best = s[j]; bestk = k + j; }
            else if (s[j] < best2) { best2 = s[j]; bestk2 = k + j; }
        }
    }
    if (best2 - best < 0.02f) {
        const float* ca = cbm + bestk  * SDIM;
        const float* cbv = cbm + bestk2 * SDIM;
        double da = 0.0, db = 0.0;
        for (int i = 0; i < SDIM; ++i) {
            const double ea = (double)x[i] - (double)ca[i];
            const double eb = (double)x[i] - (double)cbv[i];
            da += ea * ea; db += eb * eb;
        }
        if (db < da || (db == da && bestk2 < bestk)) bestk = bestk2;
    }
    const float* cbest = cbm + bestk * SDIM;
    float* o = out + (size_t)row * EMB + m * SDIM;
    #pragma unroll
    for (int i = 0; i < SDIM; i += 4)
        *reinterpret_cast<float4*>(o + i) = *reinterpret_cast<const float4*>(cbest + i);
}

extern "C" void kernel_launch(void* const* d_in, const int* in_sizes, int n_in,
                              void* d_out, int out_size, void* d_ws, size_t ws_size,
                              hipStream_t stream) {
    const float* emb = (const float*)d_in[0];
    const float* cb  = (const float*)d_in[1];
    float* out = (float*)d_out;
    const int nrows = in_sizes[0] / EMB;    // 65536 for the harness shape

    if (ws_size < WS_NEEDED || nrows != NROWS_FIX) {
        const int rowBlocks = (nrows + 255) / 256;
        pq_argmin_kernel<<<dim3(rowBlocks * NSUB), dim3(256), 0, stream>>>(emb, cb, out, nrows);
        return;
    }

    unsigned short* wsf = (unsigned short*)d_ws;
    float* wsc2 = (float*)((char*)d_ws + WS_FRAG_BYTES);

    pq_prep<<<dim3(NSUB), dim3(256), 0, stream>>>(cb, wsf, wsc2);

    const int nb = (NSUB * ROWBLKS_FIX) / 2;            // 8192 blocks of 128
    pq_mfma14<<<dim3(nb), dim3(128), 0, stream>>>(emb, cb, wsf, wsc2, out);
}

// Round 17
// 201.448 us; speedup vs baseline: 1.7168x; 1.0762x over previous
//
#include <hip/hip_runtime.h>

typedef short   bf16x8 __attribute__((ext_vector_type(8)));
typedef unsigned short u16x8 __attribute__((ext_vector_type(8)));
typedef float   f32x16 __attribute__((ext_vector_type(16)));

constexpr int NSUB  = 8;
constexpr int NCODE = 256;
constexpr int SDIM  = 96;
constexpr int EMB   = NSUB * SDIM;          // 768
constexpr float C_SHIFT = 192.0f;   // harmless shift baked into c2 (cancels in gaps)
constexpr float THR = 0.02f;        // validated recheck trigger (rounds 2-3-7..10,14)

constexpr int    CB_UNITS      = 8 * 6 * 2 * 64;                 // 6144 x 16B per subspace
constexpr size_t WS_FRAG_BYTES = (size_t)NSUB * CB_UNITS * 16;   // 786432
constexpr size_t WS_NEEDED     = WS_FRAG_BYTES + (size_t)NSUB * NCODE * 4;

__device__ __forceinline__ unsigned short f2bf(float v) {
    unsigned u = __builtin_bit_cast(unsigned, v);
    u = u + 0x7FFFu + ((u >> 16) & 1u);          // RNE
    return (unsigned short)(u >> 16);
}
__device__ __forceinline__ float bf2f(unsigned short h) {
    unsigned u = ((unsigned)h) << 16;
    return __builtin_bit_cast(float, u);
}

// ---------------- pre-kernel: pack codebook into ws (validated) ----------------
// frag unit u = ((t*6+s)*2+h)*64 + l : code=t*32+(l&31), k0=s*16+(l>>5)*8,
// value = h==0 ? hi : lo of (-cb). wsc2 = 0.5*||c||^2 + C_SHIFT (fp64).
__global__ __launch_bounds__(256) void pq_prep(const float* __restrict__ cb,
                                               unsigned short* __restrict__ wsf,
                                               float* __restrict__ wsc2)
{
    const int m   = (int)blockIdx.x;
    const int tid = (int)threadIdx.x;
    {
        const float* c = cb + ((size_t)m * NCODE + tid) * SDIM;
        double s = 0.0;
        for (int k = 0; k < SDIM; ++k) { double v = (double)c[k]; s += v * v; }
        wsc2[m * NCODE + tid] = (float)(0.5 * s + (double)C_SHIFT);
    }
    for (int i = 0; i < 24; ++i) {
        int u  = i * 256 + tid;
        int l  = u & 63;
        int c6 = u >> 6;
        int h  = c6 & 1; c6 >>= 1;
        int s  = c6 % 6;
        int t  = c6 / 6;
        int code = t * 32 + (l & 31);
        int k0   = s * 16 + (l >> 5) * 8;
        const float* src = cb + (size_t)m * NCODE * SDIM + (size_t)code * SDIM + k0;
        u16x8 o;
        #pragma unroll
        for (int j = 0; j < 8; ++j) {
            float v = -src[j];
            unsigned short hb = f2bf(v);
            o[j] = (h == 0) ? hb : f2bf(v - bf2f(hb));
        }
        *(u16x8*)(wsf + ((size_t)m * CB_UNITS + u) * 8) = o;
    }
}

// ------ main: one wave owns (m, 32 rows). NO LDS, NO barriers.           ------
// ------ Byte-identical body to R14 (206us, VGPR 76). ONLY change:        ------
// ------ m = blockIdx & 7 -> blocks of one m land on ONE XCD (round-robin ------
// ------ dispatch), keeping that XCD's 96 KB packed-cb hot in its L2.     ------
__global__ __launch_bounds__(128, 3) void pq_mfma15(
    const float* __restrict__ emb,
    const float* __restrict__ cb,
    const unsigned short* __restrict__ wsf,
    const float* __restrict__ wsc2,
    float* __restrict__ out,
    int nrows,
    int rowblks)
{
    const int tid  = (int)threadIdx.x;
    const int lane = tid & 63;
    const int hib  = lane >> 5;
    const int m    = (int)blockIdx.x & 7;               // XCD-pinned subspace
    const int rb   = ((int)blockIdx.x >> 3) * 2 + (tid >> 6);
    if (rb >= rowblks) return;
    const int row0 = rb * 32;

    const unsigned short* wb = wsf + (size_t)m * CB_UNITS * 8;
    const float* c2p = wsc2 + m * NCODE;

    // ---- load this lane's x fragments straight from emb; hi/lo split in regs ----
    // lane l holds row (l&31), dims s*16 + (l>>5)*8 + [0..8)  (validated B layout)
    bf16x8 xh[6], xl[6];
    {
        int r = row0 + (lane & 31);
        if (r >= nrows) r = nrows - 1;
        const float* xr = emb + (size_t)r * EMB + m * SDIM + hib * 8;
        #pragma unroll
        for (int s = 0; s < 6; ++s) {
            float4 v0 = *(const float4*)(xr + s * 16);
            float4 v1 = *(const float4*)(xr + s * 16 + 4);
            float v[8] = { v0.x, v0.y, v0.z, v0.w, v1.x, v1.y, v1.z, v1.w };
            #pragma unroll
            for (int j = 0; j < 8; ++j) {
                unsigned short hb = f2bf(v[j]);
                xh[s][j] = (short)hb;
                xl[s][j] = (short)f2bf(v[j] - bf2f(hb));
            }
        }
    }

    // ---- 4 t-pairs: acc init from c2, 36 MFMA, serial scan (code-ascending) ----
    float b1 = 3.4e38f, b2 = 3.4e38f;
    int   i1 = 1 << 30, i2 = 1 << 30;
    #pragma unroll 1
    for (int p = 0; p < 4; ++p) {
        const int t0 = p * 2, t1 = t0 + 1;
        f32x16 a0, a1;
        #pragma unroll
        for (int rq = 0; rq < 4; ++rq) {
            float4 q0 = *(const float4*)(c2p + t0 * 32 + rq * 8 + hib * 4);
            float4 q1 = *(const float4*)(c2p + t1 * 32 + rq * 8 + hib * 4);
            a0[rq*4+0]=q0.x; a0[rq*4+1]=q0.y; a0[rq*4+2]=q0.z; a0[rq*4+3]=q0.w;
            a1[rq*4+0]=q1.x; a1[rq*4+1]=q1.y; a1[rq*4+2]=q1.z; a1[rq*4+3]=q1.w;
        }
        __builtin_amdgcn_s_setprio(1);
        #pragma unroll
        for (int s = 0; s < 6; ++s) {
            bf16x8 ah0 = *(const bf16x8*)(wb + (size_t)((((t0 * 6 + s) * 2) + 0) * 64 + lane) * 8);
            bf16x8 al0 = *(const bf16x8*)(wb + (size_t)((((t0 * 6 + s) * 2) + 1) * 64 + lane) * 8);
            bf16x8 ah1 = *(const bf16x8*)(wb + (size_t)((((t1 * 6 + s) * 2) + 0) * 64 + lane) * 8);
            bf16x8 al1 = *(const bf16x8*)(wb + (size_t)((((t1 * 6 + s) * 2) + 1) * 64 + lane) * 8);
            a0 = __builtin_amdgcn_mfma_f32_32x32x16_bf16(ah0, xh[s], a0, 0, 0, 0);
            a1 = __builtin_amdgcn_mfma_f32_32x32x16_bf16(ah1, xh[s], a1, 0, 0, 0);
            a0 = __builtin_amdgcn_mfma_f32_32x32x16_bf16(al0, xh[s], a0, 0, 0, 0);
            a1 = __builtin_amdgcn_mfma_f32_32x32x16_bf16(al1, xh[s], a1, 0, 0, 0);
            a0 = __builtin_amdgcn_mfma_f32_32x32x16_bf16(ah0, xl[s], a0, 0, 0, 0);
            a1 = __builtin_amdgcn_mfma_f32_32x32x16_bf16(ah1, xl[s], a1, 0, 0, 0);
        }
        __builtin_amdgcn_s_setprio(0);
        // serial scan, ascending code order per lane (first-min tie rule)
        #pragma unroll
        for (int r = 0; r < 16; ++r) {
            float sv = a0[r];
            int   kv = t0 * 32 + (r & 3) + 8 * (r >> 2) + hib * 4;
            if (sv < b1)      { b2 = b1; i2 = i1; b1 = sv; i1 = kv; }
            else if (sv < b2) { b2 = sv; i2 = kv; }
        }
        #pragma unroll
        for (int r = 0; r < 16; ++r) {
            float sv = a1[r];
            int   kv = t1 * 32 + (r & 3) + 8 * (r >> 2) + hib * 4;
            if (sv < b1)      { b2 = b1; i2 = i1; b1 = sv; i1 = kv; }
            else if (sv < b2) { b2 = sv; i2 = kv; }
        }
    }
    {   // merge lane^32 partner (same rows, other hib codes) — validated code
        float ob1 = __shfl_xor(b1, 32);
        int   oi1 = __shfl_xor(i1, 32);
        float ob2 = __shfl_xor(b2, 32);
        int   oi2 = __shfl_xor(i2, 32);
        bool o1_better = (ob1 < b1) || (ob1 == b1 && oi1 < i1);
        if (o1_better) {
            bool mine_better = (b1 < ob2) || (b1 == ob2 && i1 < oi2);
            if (mine_better) { b2 = b1; i2 = i1; } else { b2 = ob2; i2 = oi2; }
            b1 = ob1; i1 = oi1;
        } else {
            if ((ob1 < b2) || (ob1 == b2 && oi1 < i2)) { b2 = ob1; i2 = oi1; }
        }
    }

    // ---- cheap top-2 fp64 recheck (validated; ~1-2% trigger; uniform 96-iter loop) ----
    {
        int grow = row0 + (lane & 31);
        if (lane < 32 && grow < nrows && (b2 - b1 < THR)) {
            const float* xr = emb + (size_t)grow * EMB + m * SDIM;
            const float* ca = cb + ((size_t)m * NCODE + i1) * SDIM;
            const float* cbv = cb + ((size_t)m * NCODE + i2) * SDIM;
            double da = 0.0, db = 0.0;
            for (int kk = 0; kk < SDIM; ++kk) {
                double ea = (double)xr[kk] - (double)ca[kk];
                double eb = (double)xr[kk] - (double)cbv[kk];
                da += ea * ea; db += eb * eb;
            }
            if (db < da || (db == da && i2 < i1)) i1 = i2;
        }
    }

    // ---- gather + coalesced write-out (24 lanes = 384B runs per row) ----
    #pragma unroll
    for (int ii = 0; ii < 12; ++ii) {
        int Q = ii * 64 + lane;                 // 768 = 32 rows x 24 float4
        int r = Q / 24, f = Q % 24;
        int grow = row0 + r;
        int k = __shfl(i1, r);                  // winner held by lane r (<32)
        if (grow < nrows) {
            float4 v = *(const float4*)(cb + ((size_t)m * NCODE + k) * SDIM + f * 4);
            *(float4*)(out + (size_t)grow * EMB + m * SDIM + f * 4) = v;
        }
    }
}

// ---------------- fallback (round-2 kernel, validated) ----------------
__global__ __launch_bounds__(256) void pq_argmin_kernel(
    const float* __restrict__ emb, const float* __restrict__ cb,
    float* __restrict__ out, int nrows)
{
    const int m   = (int)(blockIdx.x & 7);
    const int row = (int)(blockIdx.x >> 3) * 256 + (int)threadIdx.x;
    const float* __restrict__ cbm = cb + (size_t)m * (NCODE * SDIM);
    __shared__ float half_c2[NCODE];
    {
        const int k = (int)threadIdx.x;
        const float* c = cbm + k * SDIM;
        float s = 0.f;
        #pragma unroll
        for (int i = 0; i < SDIM; i += 4) {
            const float4 v = *reinterpret_cast<const float4*>(c + i);
            s = fmaf(v.x, v.x, s); s = fmaf(v.y, v.y, s);
            s = fmaf(v.z, v.z, s); s = fmaf(v.w, v.w, s);
        }
        half_c2[k] = 0.5f * s;
    }
    __syncthreads();
    if (row >= nrows) return;
    float x[SDIM];
    {
        const float* xr = emb + (size_t)row * EMB + m * SDIM;
        #pragma unroll
        for (int i = 0; i < SDIM; i += 4) {
            const float4 v = *reinterpret_cast<const float4*>(xr + i);
            x[i+0] = v.x; x[i+1] = v.y; x[i+2] = v.z; x[i+3] = v.w;
        }
    }
    float best = 3.4e38f, best2 = 3.4e38f;
    int bestk = 0, bestk2 = 0;
    #pragma unroll 1
    for (int k = 0; k < NCODE; k += 4) {
        const float* c0 = cbm + (k + 0) * SDIM;
        const float* c1 = cbm + (k + 1) * SDIM;
        const float* c2 = cbm + (k + 2) * SDIM;
        const float* c3 = cbm + (k + 3) * SDIM;
        float a0 = 0.f, a1 = 0.f, a2 = 0.f, a3 = 0.f;
        #pragma unroll
        for (int i = 0; i < SDIM; i += 4) {
            const float4 v0 = *reinterpret_cast<const float4*>(c0 + i);
            const float4 v1 = *reinterpret_cast<const float4*>(c1 + i);
            const float4 v2 = *reinterpret_cast<const float4*>(c2 + i);
            const float4 v3 = *reinterpret_cast<const float4*>(c3 + i);
            a0 = fmaf(x[i+0], v0.x, a0); a0 = fmaf(x[i+1], v0.y, a0);
            a0 = fmaf(x[i+2], v0.z, a0); a0 = fmaf(x[i+3], v0.w, a0);
            a1 = fmaf(x[i+0], v1.x, a1); a1 = fmaf(x[i+1], v1.y, a1);
            a1 = fmaf(x[i+2], v1.z, a1); a1 = fmaf(x[i+3], v1.w, a1);
            a2 = fmaf(x[i+0], v2.x, a2); a2 = fmaf(x[i+1], v2.y, a2);
            a2 = fmaf(x[i+2], v2.z, a2); a2 = fmaf(x[i+3], v2.w, a2);
            a3 = fmaf(x[i+0], v3.x, a3); a3 = fmaf(x[i+1], v3.y, a3);
            a3 = fmaf(x[i+2], v3.z, a3); a3 = fmaf(x[i+3], v3.w, a3);
        }
        const float s[4] = { half_c2[k+0] - a0, half_c2[k+1] - a1,
                             half_c2[k+2] - a2, half_c2[k+3] - a3 };
        #pragma unroll
        for (int j = 0; j < 4; ++j) {
            if (s[j] < best)       { best2 = best; bestk2 = bestk; best = s[j]; bestk = k + j; }
            else if (s[j] < best2) { best2 = s[j]; bestk2 = k + j; }
        }
    }
    if (best2 - best < 0.02f) {
        const float* ca = cbm + bestk  * SDIM;
        const float* cbv = cbm + bestk2 * SDIM;
        double da = 0.0, db = 0.0;
        for (int i = 0; i < SDIM; ++i) {
            const double ea = (double)x[i] - (double)ca[i];
            const double eb = (double)x[i] - (double)cbv[i];
            da += ea * ea; db += eb * eb;
        }
        if (db < da || (db == da && bestk2 < bestk)) bestk = bestk2;
    }
    const float* cbest = cbm + bestk * SDIM;
    float* o = out + (size_t)row * EMB + m * SDIM;
    #pragma unroll
    for (int i = 0; i < SDIM; i += 4)
        *reinterpret_cast<float4*>(o + i) = *reinterpret_cast<const float4*>(cbest + i);
}

extern "C" void kernel_launch(void* const* d_in, const int* in_sizes, int n_in,
                              void* d_out, int out_size, void* d_ws, size_t ws_size,
                              hipStream_t stream) {
    const float* emb = (const float*)d_in[0];
    const float* cb  = (const float*)d_in[1];
    float* out = (float*)d_out;
    const int nrows = in_sizes[0] / EMB;    // 65536

    if (ws_size < WS_NEEDED) {
        const int rowBlocks = (nrows + 255) / 256;
        pq_argmin_kernel<<<dim3(rowBlocks * NSUB), dim3(256), 0, stream>>>(emb, cb, out, nrows);
        return;
    }

    unsigned short* wsf = (unsigned short*)d_ws;
    float* wsc2 = (float*)((char*)d_ws + WS_FRAG_BYTES);

    pq_prep<<<dim3(NSUB), dim3(256), 0, stream>>>(cb, wsf, wsc2);

    const int rowblks = (nrows + 31) / 32;              // 2048
    const int nb      = ((rowblks + 1) / 2) * NSUB;     // 8192 blocks of 128
    pq_mfma15<<<dim3(nb), dim3(128), 0, stream>>>(emb, cb, wsf, wsc2, out, nrows, rowblks);
}